// Round 15
// baseline (309.184 us; speedup 1.0000x reference)
//
#include <hip/hip_runtime.h>
#include <cmath>

// RoPEAttention: S=4096, D=2048, base=10000
// GEMM core: 256x256 tile, BK=64, 8 waves (2Mx4N), counted vmcnt(6), XOR LDS
// swizzle, s_setprio around MFMA. r15: quadrant MFMAs split by K-slice (ks)
// and ds_reads SPREAD across all 4 barrier segments per buf (was clumped
// 16/8/0/0 -> LDS port serialized in read windows while matrix pipe idled).
// Same registers (16 frags, same slots), same barriers/STAGE/vmcnt skeleton.
// Per-segment consumers force lgkm drain >=1 barrier before each region's
// overwriting STAGE (region-death audit in journal). Intermediates f16.
// NOTE (journal): T1 XCD swizzle regressed; max-lead staging regressed (r9);
// NT C-stores regressed (r10); fused RoPE/V epilogue corrupted (r4-6).

typedef _Float16 f16;
typedef __attribute__((ext_vector_type(2))) _Float16 f16x2;
typedef __attribute__((ext_vector_type(4))) _Float16 f16x4;
typedef __attribute__((ext_vector_type(8))) _Float16 f16x8;
typedef __attribute__((ext_vector_type(4))) float f32x4;

#define GLD16(g, loff)                                                         \
  __builtin_amdgcn_global_load_lds(                                            \
      (const __attribute__((address_space(1))) void*)(g),                      \
      (__attribute__((address_space(3))) void*)(smem + (loff)), 16, 0, 0)

#define STAGE(BUFOFF, REG, PL0, PL1, KT)                                       \
  do {                                                                         \
    GLD16((PL0) + (KT), (BUFOFF) + (REG) + d0);                                \
    GLD16((PL1) + (KT), (BUFOFF) + (REG) + d1);                                \
  } while (0)

#define BAR() __builtin_amdgcn_s_barrier()
#define WAITVM6() asm volatile("s_waitcnt vmcnt(6)" ::: "memory")
#define WAITVM0() asm volatile("s_waitcnt vmcnt(0)" ::: "memory")

// 4 ds_read_b128: A fragments for M-quadrant MQ, K-slice KS
#define LOAD_A_KS(BUF, MQ, KS)                                                 \
  _Pragma("unroll") for (int i = 0; i < 4; ++i)                                \
      af[i][KS] = *(const f16x8*)(smem + (BUF) + rba +                         \
                                  (((MQ) * 64 + i * 16) << 7) +                \
                                  ((KS) ? kxa1 : kxa0));

// 2 ds_read_b128: B fragments for N-quadrant NQ, K-slice KS
#define LOAD_B_KS(BUF, NQ, BF, KS)                                             \
  _Pragma("unroll") for (int j = 0; j < 2; ++j)                                \
      BF[j][KS] = *(const f16x8*)(smem + (BUF) + rbb +                         \
                                  (((NQ) * 32 + j * 16) << 7) +                \
                                  ((KS) ? kxa1 : kxa0));

// 8 MFMA: quadrant (MQ,NQ), single K-slice KS
#define MFMA_QK(MQ, NQ, BF, KS)                                                \
  __builtin_amdgcn_s_setprio(1);                                               \
  _Pragma("unroll") for (int i = 0; i < 4; ++i)                                \
  _Pragma("unroll") for (int j = 0; j < 2; ++j)                                \
    acc[(MQ) * 4 + i][(NQ) * 2 + j] = __builtin_amdgcn_mfma_f32_16x16x32_f16(  \
        af[i][KS], BF[j][KS], acc[(MQ) * 4 + i][(NQ) * 2 + j], 0, 0, 0);       \
  __builtin_amdgcn_s_setprio(0)

// C[M,N] = alpha * A[M,K] @ B[N,K]^T, row stride Kstride for A and B.
// Split-K: blockIdx.z offsets A,B by z*K and C by z*M*N (partials).
// M,N % 256 == 0, K % 128 == 0. grid = (N/256, M/256, splits), block = 512.
template <typename OutT>
__global__ __launch_bounds__(512) void gemm256_8ph(
    const f16* __restrict__ A, const f16* __restrict__ B,
    OutT* __restrict__ C, int M, int N, int K, int Kstride, float alpha) {
  __shared__ __align__(16) char smem[131072];
  const int tid = threadIdx.x;
  const int wave = tid >> 6, lane = tid & 63;
  const int wm = wave >> 2, wn = wave & 3;  // 2 x 4 wave grid
  const int l15 = lane & 15, kq = lane >> 4;
  const int bm = blockIdx.y << 8, bn = blockIdx.x << 8;

  // split-K offsets (zero when gridDim.z == 1)
  const size_t zofs = (size_t)blockIdx.z * (size_t)K;
  A += zofs;
  B += zofs;
  C += (size_t)blockIdx.z * (size_t)M * N;

  f32x4 acc[8][4];
#pragma unroll
  for (int m = 0; m < 8; ++m)
#pragma unroll
    for (int n = 0; n < 4; ++n) acc[m][n] = f32x4{0.f, 0.f, 0.f, 0.f};

  // staging: half-tile = 1024 16B-chunks; chunk c -> (row=c>>3, slot=c&7);
  // source k8 = slot ^ (row&7)  (swizzle on the SOURCE, LDS dest linear).
  const int c0 = wave * 64 + lane;
  const int c1 = 512 + c0;
  const int r0 = c0 >> 3, q0 = ((c0 & 7) ^ (r0 & 7)) << 3;
  const int r1 = c1 >> 3, q1 = ((c1 & 7) ^ (r1 & 7)) << 3;
  const f16* pa0 = A + (size_t)(bm + r0) * Kstride + q0;        // A half0
  const f16* pa1 = A + (size_t)(bm + r1) * Kstride + q1;
  const f16* pA0 = A + (size_t)(bm + 128 + r0) * Kstride + q0;  // A half1
  const f16* pA1 = A + (size_t)(bm + 128 + r1) * Kstride + q1;
  const f16* pb0 = B + (size_t)(bn + r0) * Kstride + q0;        // B half0
  const f16* pb1 = B + (size_t)(bn + r1) * Kstride + q1;
  const f16* pB0 = B + (size_t)(bn + 128 + r0) * Kstride + q0;  // B half1
  const f16* pB1 = B + (size_t)(bn + 128 + r1) * Kstride + q1;
  const int d0 = wave << 10;
  const int d1 = 8192 + d0;

  // ds_read addressing (XOR swizzle on the read side)
  const int swz = l15 & 7;
  const int kxa0 = (kq ^ swz) << 4;
  const int kxa1 = ((4 + kq) ^ swz) << 4;
  const int rba = (wm * 128 + l15) << 7;
  const int rbb = 32768 + ((wn * 64 + l15) << 7);

  const int nt2 = K >> 7;  // each iteration covers 2 K-tiles of 64

  // prologue: t0 fully, t1 {B0,B1,A0}; vmcnt(6) lands t0.
  STAGE(0, 0, pa0, pa1, 0);
  STAGE(0, 16384, pA0, pA1, 0);
  STAGE(0, 32768, pb0, pb1, 0);
  STAGE(0, 49152, pB0, pB1, 0);
  STAGE(65536, 32768, pb0, pb1, 64);
  STAGE(65536, 49152, pB0, pB1, 64);
  STAGE(65536, 0, pa0, pa1, 64);
  WAITVM6();
  BAR();

  f16x8 af[4][2], bf0[2][2], bf1[2][2];

  for (int it = 0; it < nt2; ++it) {
    const int kt = it << 7;
    const bool full = (it != nt2 - 1);
    // ======== buf0 (tile 2it) ========
    // S1: reads 12, MFMA 16; stage t+1:A1
    LOAD_A_KS(0, 0, 0);
    LOAD_B_KS(0, 0, bf0, 0);
    STAGE(65536, 16384, pA0, pA1, kt + 64);
    MFMA_QK(0, 0, bf0, 0);
    LOAD_B_KS(0, 1, bf1, 0);
    LOAD_A_KS(0, 0, 1);
    MFMA_QK(0, 1, bf1, 0);
    BAR();
    // S2: reads 8, MFMA 16
    LOAD_B_KS(0, 0, bf0, 1);
    LOAD_B_KS(0, 1, bf1, 1);
    MFMA_QK(0, 0, bf0, 1);
    LOAD_A_KS(0, 1, 0);
    MFMA_QK(0, 1, bf1, 1);  // last B-reg consumer -> B reads drained
    BAR();
    // S3: reads 4, MFMA 16; stage t+2:B0 (B-region dead since S2)
    if (full) STAGE(0, 32768, pb0, pb1, kt + 128);
    MFMA_QK(1, 1, bf1, 0);
    LOAD_A_KS(0, 1, 1);
    MFMA_QK(1, 1, bf1, 1);  // consumes af1k1 -> A reads drained in-segment
    BAR();
    // S4: MFMA 16; stage t+2:{B1,A0}; vmcnt(6) lands tile 2it+1
    if (full) {
      STAGE(0, 49152, pB0, pB1, kt + 128);
      STAGE(0, 0, pa0, pa1, kt + 128);
    }
    MFMA_QK(1, 0, bf0, 0);
    MFMA_QK(1, 0, bf0, 1);
    WAITVM6();
    BAR();
    // ======== buf1 (tile 2it+1) ========
    // S1: reads 12, MFMA 16; stage t+2:A1
    LOAD_A_KS(65536, 0, 0);
    LOAD_B_KS(65536, 0, bf0, 0);
    if (full) STAGE(0, 16384, pA0, pA1, kt + 128);
    MFMA_QK(0, 0, bf0, 0);
    LOAD_B_KS(65536, 1, bf1, 0);
    LOAD_A_KS(65536, 0, 1);
    MFMA_QK(0, 1, bf1, 0);
    BAR();
    // S2
    LOAD_B_KS(65536, 0, bf0, 1);
    LOAD_B_KS(65536, 1, bf1, 1);
    MFMA_QK(0, 0, bf0, 1);
    LOAD_A_KS(65536, 1, 0);
    MFMA_QK(0, 1, bf1, 1);
    BAR();
    // S3: stage t+3:B0
    if (full) STAGE(65536, 32768, pb0, pb1, kt + 192);
    MFMA_QK(1, 1, bf1, 0);
    LOAD_A_KS(65536, 1, 1);
    MFMA_QK(1, 1, bf1, 1);
    BAR();
    // S4: stage t+3:{B1,A0}; vmcnt lands tile 2it+2 (or drain at end)
    if (full) {
      STAGE(65536, 49152, pB0, pB1, kt + 192);
      STAGE(65536, 0, pa0, pa1, kt + 192);
    }
    MFMA_QK(1, 0, bf0, 0);
    MFMA_QK(1, 0, bf0, 1);
    if (full) WAITVM6(); else WAITVM0();
    BAR();
  }

  // epilogue: C/D layout col = lane&15, row = (lane>>4)*4 + reg
  const int orow = bm + wm * 128 + (kq << 2);
  const int ocol = bn + wn * 64 + l15;
#pragma unroll
  for (int m = 0; m < 8; ++m)
#pragma unroll
    for (int n = 0; n < 4; ++n)
#pragma unroll
      for (int r = 0; r < 4; ++r)
        C[(size_t)(orow + m * 16 + r) * N + (ocol + n * 16)] =
            (OutT)(acc[m][n][r] * alpha);
}

// fused fp32->fp16 cast of x (2M float4) + Wq|Wk|Wv (3M float4) + freq init
// (blocks 0..3: freqs[j] = 10000^(-j/1024); -log2(1e4)/1024 = -0.0129762816...)
__global__ __launch_bounds__(256) void cast_all_kernel(
    const float* __restrict__ x, const float* __restrict__ wq,
    const float* __restrict__ wk, const float* __restrict__ wv,
    f16* __restrict__ xh, f16* __restrict__ wh, double* __restrict__ freqs) {
  int i = blockIdx.x * 256 + threadIdx.x;  // float4 index over 5M
  if (i < 1024) freqs[i] = exp2((double)i * -0.012976281620653758);
  float4 v;
  f16x4* dst;
  if (i < 2097152) {
    v = reinterpret_cast<const float4*>(x)[i];
    dst = reinterpret_cast<f16x4*>(xh) + i;
  } else {
    int j = i - 2097152;
    int w = j >> 20, r = j & 1048575;
    const float* s = (w == 0) ? wq : (w == 1 ? wk : wv);
    v = reinterpret_cast<const float4*>(s)[r];
    dst = reinterpret_cast<f16x4*>(wh) + j;
  }
  *dst = f16x4{(f16)v.x, (f16)v.y, (f16)v.z, (f16)v.w};
}

// Merged RoPE (blocks 0..16383) + V partial-reduce/transpose (rest).
// rope: qk f16 [S][4096] (cols 0..2047=Q, 2048..4095=K) -> qr, kr f16.
// vred: vp = 2 x [S][2048] f16 partials -> vt[d][s] f16.
__global__ __launch_bounds__(256) void rope_vred_kernel(
    const f16* __restrict__ qk, const double* __restrict__ freqs,
    f16* __restrict__ qr, f16* __restrict__ kr,
    const f16* __restrict__ vp, f16* __restrict__ vt) {
  __shared__ float tile[32][33];
  const int bid = blockIdx.x;
  if (bid < 16384) {
    int idx = bid * 256 + threadIdx.x;  // s*1024 + j
    int j = idx & 1023;
    int s = idx >> 10;
    double ang = (double)s * freqs[j];
    ang -= 6.2831853071795864769 * floor(ang * 0.15915494309189533577);
    float c, sn;
    sincosf((float)ang, &sn, &c);
    const f16x2* qp = reinterpret_cast<const f16x2*>(qk + (size_t)s * 4096);
    const f16x2* kp =
        reinterpret_cast<const f16x2*>(qk + (size_t)s * 4096 + 2048);
    f16x2 q2 = qp[j];
    f16x2 k2 = kp[j];
    const float qx = (float)q2[0], qy = (float)q2[1];
    const float kx = (float)k2[0], ky = (float)k2[1];
    f16x2 qo = {(f16)(qx * c - qy * sn), (f16)(qx * sn + qy * c)};
    f16x2 ko = {(f16)(kx * c - ky * sn), (f16)(kx * sn + ky * c)};
    reinterpret_cast<f16x2*>(qr)[idx] = qo;
    reinterpret_cast<f16x2*>(kr)[idx] = ko;
  } else {
    const int vb = bid - 16384;            // 0..8191 = 128 x 64
    const int sblk = (vb & 127) * 32, dblk = (vb >> 7) * 32;
    const int tx = threadIdx.x & 31, ty = threadIdx.x >> 5;  // 32 x 8
#pragma unroll
    for (int i = 0; i < 4; ++i) {
      const size_t idx = (size_t)(sblk + ty + i * 8) * 2048 + dblk + tx;
      tile[ty + i * 8][tx] = (float)vp[idx] + (float)vp[idx + 8388608];
    }
    __syncthreads();
#pragma unroll
    for (int i = 0; i < 4; ++i)
      vt[(size_t)(dblk + ty + i * 8) * 4096 + sblk + tx] =
          (f16)tile[tx][ty + i * 8];
  }
}

// Row softmax: read f16 scores [row][4096], write fp32 weights (graded)
// and f16 copy for the PV GEMM.
__global__ __launch_bounds__(256) void softmax_kernel(
    const f16* __restrict__ sc, float* __restrict__ weights,
    f16* __restrict__ wh) {
  const int row = blockIdx.x;
  const f16x8* p = reinterpret_cast<const f16x8*>(sc + (size_t)row * 4096);
  const int tid = threadIdx.x;
  float v[16];
  float lmax = -3.0e38f;
#pragma unroll
  for (int i = 0; i < 2; ++i) {
    f16x8 h = p[tid + i * 256];
#pragma unroll
    for (int t = 0; t < 8; ++t) {
      v[i * 8 + t] = (float)h[t];
      lmax = fmaxf(lmax, v[i * 8 + t]);
    }
  }
#pragma unroll
  for (int o = 32; o >= 1; o >>= 1) lmax = fmaxf(lmax, __shfl_xor(lmax, o));
  __shared__ float redm[4], reds[4];
  if ((tid & 63) == 0) redm[tid >> 6] = lmax;
  __syncthreads();
  const float gmax = fmaxf(fmaxf(redm[0], redm[1]), fmaxf(redm[2], redm[3]));
  float lsum = 0.f;
#pragma unroll
  for (int t = 0; t < 16; ++t) {
    v[t] = expf(v[t] - gmax);
    lsum += v[t];
  }
#pragma unroll
  for (int o = 32; o >= 1; o >>= 1) lsum += __shfl_xor(lsum, o);
  if ((tid & 63) == 0) reds[tid >> 6] = lsum;
  __syncthreads();
  const float inv = 1.0f / (reds[0] + reds[1] + reds[2] + reds[3]);
  float* wrow = weights + (size_t)row * 4096;
  f16* hrow = wh + (size_t)row * 4096;
#pragma unroll
  for (int i = 0; i < 2; ++i) {
    const int base = (tid + i * 256) * 8;
    float w[8];
    f16x8 h;
#pragma unroll
    for (int t = 0; t < 8; ++t) {
      w[t] = v[i * 8 + t] * inv;
      h[t] = (f16)w[t];
    }
    *reinterpret_cast<float4*>(wrow + base) =
        make_float4(w[0], w[1], w[2], w[3]);
    *reinterpret_cast<float4*>(wrow + base + 4) =
        make_float4(w[4], w[5], w[6], w[7]);
    *reinterpret_cast<f16x8*>(hrow + base) = h;
  }
}

// out(fp32) = (float)p[0..8M) + (float)p[8M..16M), f16x8-vectorized
__global__ __launch_bounds__(256) void reduce2_kernel(
    const f16* __restrict__ p, float* __restrict__ out) {
  int i = blockIdx.x * 256 + threadIdx.x;  // f16x8 unit over 1M
  f16x8 a = reinterpret_cast<const f16x8*>(p)[i];
  f16x8 b = reinterpret_cast<const f16x8*>(p + 8388608)[i];
  float4 o0, o1;
#pragma unroll
  for (int t = 0; t < 4; ++t) ((float*)&o0)[t] = (float)a[t] + (float)b[t];
#pragma unroll
  for (int t = 0; t < 4; ++t) ((float*)&o1)[t] = (float)a[4 + t] + (float)b[4 + t];
  reinterpret_cast<float4*>(out)[2 * i] = o0;
  reinterpret_cast<float4*>(out)[2 * i + 1] = o1;
}

extern "C" void kernel_launch(void* const* d_in, const int* in_sizes, int n_in,
                              void* d_out, int out_size, void* d_ws,
                              size_t ws_size, hipStream_t stream) {
  const int S = 4096, D = 2048;
  const float* x = (const float*)d_in[0];
  const float* Wq = (const float*)d_in[1];
  const float* Wk = (const float*)d_in[2];
  const float* Wv = (const float*)d_in[3];
  float* out = (float*)d_out;            // [S, D]
  float* weights = out + (size_t)S * D;  // [S, S]

  f16* x_h = (f16*)d_ws;                           // S*D f16 (16MB)
  f16* w_h = x_h + (size_t)S * D;                  // 3*D*D f16 (24MB)
  f16* qk_h = w_h + (size_t)3 * D * D;             // S x 4096 f16 (32MB)
  f16* vp_h = qk_h + (size_t)S * 4096;             // 2 x S*D f16 (32MB)
  f16* qr = vp_h + (size_t)2 * S * D;              // S*D (16MB)
  f16* kr = qr + (size_t)S * D;                    // S*D (16MB)
  f16* vt = kr + (size_t)S * D;                    // D x S (16MB)
  f16* wsm = vt + (size_t)S * D;                   // S*S (32MB)
  double* freqs = (double*)(wsm + (size_t)S * S);  // 1024
  f16* sch = vp_h;   // f16 scores scratch (32MB; vp dead after vred)
  f16* pvp_h = qk_h; // PV f16 partials (32MB; qk dead after rope)

  cast_all_kernel<<<20480, 256, 0, stream>>>(x, Wq, Wk, Wv, x_h, w_h, freqs);

  // QK = x @ [Wq;Wk]^T -> f16: M=4096, N=4096, K=2048, 256 blocks
  gemm256_8ph<f16><<<dim3(16, 16, 1), 512, 0, stream>>>(
      x_h, w_h, qk_h, S, 2 * D, D, D, 1.0f);
  // V = x @ Wv^T, split-K=2 -> f16 partials: 256 blocks
  gemm256_8ph<f16><<<dim3(8, 16, 2), 512, 0, stream>>>(
      x_h, w_h + (size_t)2 * D * D, vp_h, S, D, D / 2, D, 1.0f);

  // RoPE (16384 blocks) + V reduce/transpose (8192 blocks), one launch
  rope_vred_kernel<<<24576, 256, 0, stream>>>(qk_h, freqs, qr, kr, vp_h, vt);

  // scores = Q_rot @ K_rot^T / sqrt(D) -> f16 scratch: 256 blocks
  gemm256_8ph<f16><<<dim3(16, 16, 1), 512, 0, stream>>>(
      qr, kr, sch, S, S, D, D, 0.02209708691207961f);
  softmax_kernel<<<S, 256, 0, stream>>>(sch, weights, wsm);

  // output = wsm[S,S] @ vt[D,S]^T, split-K=2 -> f16 partials: 256 blocks
  gemm256_8ph<f16><<<dim3(8, 16, 2), 512, 0, stream>>>(
      wsm, vt, pvp_h, S, D, S / 2, S, 1.0f);
  reduce2_kernel<<<4096, 256, 0, stream>>>(pvp_h, out);
}

// Round 17
// 306.764 us; speedup vs baseline: 1.0079x; 1.0079x over previous
//
#include <hip/hip_runtime.h>
#include <cmath>

// RoPEAttention: S=4096, D=2048, base=10000
// GEMM core (FROZEN at r15 plateau ~1050 TF/round): 256x256 tile, BK=64,
// 8 waves, counted vmcnt(6), XOR LDS swizzle, setprio, K-slice-split MFMA.
// r17 FIX: buf0-S4 wait restored to `full ? vmcnt(6) : vmcnt(0)` -- r15
// accidentally made it unconditional vmcnt(6); in the FINAL iteration that
// leaves 6 of buf1's staging loads (B0/B1/A0/A1) unlanded when S5-S8 read
// buf1 => latent race. Usually won (r15 passed); r16's combined launch
// shifted timing and a timed replay lost it (first-call absmax passed,
// replay re-validation failed => nondeterminism signature).
// r16 features kept: QK+V in one launch (MODE=1, z=1 routes to V split-K
// via entry index math only); rope vectorized x4 (f16x8, one row/block).
// Intermediates f16; graded outputs fp32.
// NOTE (journal): T1 XCD swizzle regressed; max-lead staging regressed (r9);
// NT C-stores regressed (r10); fused RoPE/V epilogue corrupted (r4-6).

typedef _Float16 f16;
typedef __attribute__((ext_vector_type(2))) _Float16 f16x2;
typedef __attribute__((ext_vector_type(4))) _Float16 f16x4;
typedef __attribute__((ext_vector_type(8))) _Float16 f16x8;
typedef __attribute__((ext_vector_type(4))) float f32x4;

#define GLD16(g, loff)                                                         \
  __builtin_amdgcn_global_load_lds(                                            \
      (const __attribute__((address_space(1))) void*)(g),                      \
      (__attribute__((address_space(3))) void*)(smem + (loff)), 16, 0, 0)

#define STAGE(BUFOFF, REG, PL0, PL1, KT)                                       \
  do {                                                                         \
    GLD16((PL0) + (KT), (BUFOFF) + (REG) + d0);                                \
    GLD16((PL1) + (KT), (BUFOFF) + (REG) + d1);                                \
  } while (0)

#define BAR() __builtin_amdgcn_s_barrier()
#define WAITVM6() asm volatile("s_waitcnt vmcnt(6)" ::: "memory")
#define WAITVM0() asm volatile("s_waitcnt vmcnt(0)" ::: "memory")

// 4 ds_read_b128: A fragments for M-quadrant MQ, K-slice KS
#define LOAD_A_KS(BUF, MQ, KS)                                                 \
  _Pragma("unroll") for (int i = 0; i < 4; ++i)                                \
      af[i][KS] = *(const f16x8*)(smem + (BUF) + rba +                         \
                                  (((MQ) * 64 + i * 16) << 7) +                \
                                  ((KS) ? kxa1 : kxa0));

// 2 ds_read_b128: B fragments for N-quadrant NQ, K-slice KS
#define LOAD_B_KS(BUF, NQ, BF, KS)                                             \
  _Pragma("unroll") for (int j = 0; j < 2; ++j)                                \
      BF[j][KS] = *(const f16x8*)(smem + (BUF) + rbb +                         \
                                  (((NQ) * 32 + j * 16) << 7) +                \
                                  ((KS) ? kxa1 : kxa0));

// 8 MFMA: quadrant (MQ,NQ), single K-slice KS
#define MFMA_QK(MQ, NQ, BF, KS)                                                \
  __builtin_amdgcn_s_setprio(1);                                               \
  _Pragma("unroll") for (int i = 0; i < 4; ++i)                                \
  _Pragma("unroll") for (int j = 0; j < 2; ++j)                                \
    acc[(MQ) * 4 + i][(NQ) * 2 + j] = __builtin_amdgcn_mfma_f32_16x16x32_f16(  \
        af[i][KS], BF[j][KS], acc[(MQ) * 4 + i][(NQ) * 2 + j], 0, 0, 0);       \
  __builtin_amdgcn_s_setprio(0)

// C[M,N] = alpha * A[M,K] @ B[N,K]^T, row stride Kstride for A and B.
// MODE=0: split-K via blockIdx.z (offsets A,B by z*K, C by z*M*N).
// MODE=1 (QKV combo): z=0 -> as passed (QK, N=4096 K=2048);
//   z=1 -> V split-K: B=B2, C=C2, N=2048, K=1024, kz=bx>>3, bn=(bx&7)*256.
// grid = (N/256, M/256, z), block = 512.
template <typename OutT, int MODE>
__global__ __launch_bounds__(512) void gemm256_8ph(
    const f16* A, const f16* B, OutT* C, int M, int N, int K, int Kstride,
    float alpha, const f16* B2, OutT* C2) {
  __shared__ __align__(16) char smem[131072];
  const int tid = threadIdx.x;
  const int wave = tid >> 6, lane = tid & 63;
  const int wm = wave >> 2, wn = wave & 3;  // 2 x 4 wave grid
  const int l15 = lane & 15, kq = lane >> 4;
  const int bm = blockIdx.y << 8;
  int bn = blockIdx.x << 8;

  if constexpr (MODE == 1) {
    if (blockIdx.z == 1) {  // V: split-K=2 over bx
      const int kz = blockIdx.x >> 3;
      B = B2;
      C = C2;
      N = 2048;
      K = 1024;
      bn = (blockIdx.x & 7) << 8;
      const size_t ko = (size_t)kz * 1024;
      A += ko;
      B += ko;
      C += (size_t)kz * (size_t)M * 2048;
    }
  } else {
    const size_t zofs = (size_t)blockIdx.z * (size_t)K;
    A += zofs;
    B += zofs;
    C += (size_t)blockIdx.z * (size_t)M * N;
  }

  f32x4 acc[8][4];
#pragma unroll
  for (int m = 0; m < 8; ++m)
#pragma unroll
    for (int n = 0; n < 4; ++n) acc[m][n] = f32x4{0.f, 0.f, 0.f, 0.f};

  // staging: half-tile = 1024 16B-chunks; chunk c -> (row=c>>3, slot=c&7);
  // source k8 = slot ^ (row&7)  (swizzle on the SOURCE, LDS dest linear).
  const int c0 = wave * 64 + lane;
  const int c1 = 512 + c0;
  const int r0 = c0 >> 3, q0 = ((c0 & 7) ^ (r0 & 7)) << 3;
  const int r1 = c1 >> 3, q1 = ((c1 & 7) ^ (r1 & 7)) << 3;
  const f16* pa0 = A + (size_t)(bm + r0) * Kstride + q0;        // A half0
  const f16* pa1 = A + (size_t)(bm + r1) * Kstride + q1;
  const f16* pA0 = A + (size_t)(bm + 128 + r0) * Kstride + q0;  // A half1
  const f16* pA1 = A + (size_t)(bm + 128 + r1) * Kstride + q1;
  const f16* pb0 = B + (size_t)(bn + r0) * Kstride + q0;        // B half0
  const f16* pb1 = B + (size_t)(bn + r1) * Kstride + q1;
  const f16* pB0 = B + (size_t)(bn + 128 + r0) * Kstride + q0;  // B half1
  const f16* pB1 = B + (size_t)(bn + 128 + r1) * Kstride + q1;
  const int d0 = wave << 10;
  const int d1 = 8192 + d0;

  // ds_read addressing (XOR swizzle on the read side)
  const int swz = l15 & 7;
  const int kxa0 = (kq ^ swz) << 4;
  const int kxa1 = ((4 + kq) ^ swz) << 4;
  const int rba = (wm * 128 + l15) << 7;
  const int rbb = 32768 + ((wn * 64 + l15) << 7);

  const int nt2 = K >> 7;  // each iteration covers 2 K-tiles of 64

  // prologue: t0 fully, t1 {B0,B1,A0}; vmcnt(6) lands t0.
  STAGE(0, 0, pa0, pa1, 0);
  STAGE(0, 16384, pA0, pA1, 0);
  STAGE(0, 32768, pb0, pb1, 0);
  STAGE(0, 49152, pB0, pB1, 0);
  STAGE(65536, 32768, pb0, pb1, 64);
  STAGE(65536, 49152, pB0, pB1, 64);
  STAGE(65536, 0, pa0, pa1, 64);
  WAITVM6();
  BAR();

  f16x8 af[4][2], bf0[2][2], bf1[2][2];

  for (int it = 0; it < nt2; ++it) {
    const int kt = it << 7;
    const bool full = (it != nt2 - 1);
    // ======== buf0 (tile 2it) ========
    LOAD_A_KS(0, 0, 0);
    LOAD_B_KS(0, 0, bf0, 0);
    STAGE(65536, 16384, pA0, pA1, kt + 64);
    MFMA_QK(0, 0, bf0, 0);
    LOAD_B_KS(0, 1, bf1, 0);
    LOAD_A_KS(0, 0, 1);
    MFMA_QK(0, 1, bf1, 0);
    BAR();
    LOAD_B_KS(0, 0, bf0, 1);
    LOAD_B_KS(0, 1, bf1, 1);
    MFMA_QK(0, 0, bf0, 1);
    LOAD_A_KS(0, 1, 0);
    MFMA_QK(0, 1, bf1, 1);  // last B-reg consumer -> B reads drained
    BAR();
    if (full) STAGE(0, 32768, pb0, pb1, kt + 128);
    MFMA_QK(1, 1, bf1, 0);
    LOAD_A_KS(0, 1, 1);
    MFMA_QK(1, 1, bf1, 1);
    BAR();
    if (full) {
      STAGE(0, 49152, pB0, pB1, kt + 128);
      STAGE(0, 0, pa0, pa1, kt + 128);
    }
    MFMA_QK(1, 0, bf0, 0);
    MFMA_QK(1, 0, bf0, 1);
    if (full) WAITVM6(); else WAITVM0();  // r17 FIX: final iter must drain
    BAR();                                // ALL of buf1 before S5-S8 reads
    // ======== buf1 (tile 2it+1) ========
    LOAD_A_KS(65536, 0, 0);
    LOAD_B_KS(65536, 0, bf0, 0);
    if (full) STAGE(0, 16384, pA0, pA1, kt + 128);
    MFMA_QK(0, 0, bf0, 0);
    LOAD_B_KS(65536, 1, bf1, 0);
    LOAD_A_KS(65536, 0, 1);
    MFMA_QK(0, 1, bf1, 0);
    BAR();
    LOAD_B_KS(65536, 0, bf0, 1);
    LOAD_B_KS(65536, 1, bf1, 1);
    MFMA_QK(0, 0, bf0, 1);
    LOAD_A_KS(65536, 1, 0);
    MFMA_QK(0, 1, bf1, 1);
    BAR();
    if (full) STAGE(65536, 32768, pb0, pb1, kt + 192);
    MFMA_QK(1, 1, bf1, 0);
    LOAD_A_KS(65536, 1, 1);
    MFMA_QK(1, 1, bf1, 1);
    BAR();
    if (full) {
      STAGE(65536, 49152, pB0, pB1, kt + 192);
      STAGE(65536, 0, pa0, pa1, kt + 192);
    }
    MFMA_QK(1, 0, bf0, 0);
    MFMA_QK(1, 0, bf0, 1);
    if (full) WAITVM6();
    BAR();
  }

  // epilogue: C/D layout col = lane&15, row = (lane>>4)*4 + reg
  const int orow = bm + wm * 128 + (kq << 2);
  const int ocol = bn + wn * 64 + l15;
#pragma unroll
  for (int m = 0; m < 8; ++m)
#pragma unroll
    for (int n = 0; n < 4; ++n)
#pragma unroll
      for (int r = 0; r < 4; ++r)
        C[(size_t)(orow + m * 16 + r) * N + (ocol + n * 16)] =
            (OutT)(acc[m][n][r] * alpha);
}

// fused fp32->fp16 cast of x (2M float4) + Wq|Wk|Wv (3M float4) + freq init
// (blocks 0..3: freqs[j] = 10000^(-j/1024); -log2(1e4)/1024 = -0.0129762816...)
__global__ __launch_bounds__(256) void cast_all_kernel(
    const float* __restrict__ x, const float* __restrict__ wq,
    const float* __restrict__ wk, const float* __restrict__ wv,
    f16* __restrict__ xh, f16* __restrict__ wh, double* __restrict__ freqs) {
  int i = blockIdx.x * 256 + threadIdx.x;  // float4 index over 5M
  if (i < 1024) freqs[i] = exp2((double)i * -0.012976281620653758);
  float4 v;
  f16x4* dst;
  if (i < 2097152) {
    v = reinterpret_cast<const float4*>(x)[i];
    dst = reinterpret_cast<f16x4*>(xh) + i;
  } else {
    int j = i - 2097152;
    int w = j >> 20, r = j & 1048575;
    const float* s = (w == 0) ? wq : (w == 1 ? wk : wv);
    v = reinterpret_cast<const float4*>(s)[r];
    dst = reinterpret_cast<f16x4*>(wh) + j;
  }
  *dst = f16x4{(f16)v.x, (f16)v.y, (f16)v.z, (f16)v.w};
}

// Merged RoPE (blocks 0..4095: one S-row per block, 4 pairs/thread f16x8) +
// V partial-reduce/transpose (blocks 4096..12287).
// rope: qk f16 [S][4096] (cols 0..2047=Q, 2048..4095=K) -> qr, kr f16.
// vred: vp = 2 x [S][2048] f16 partials -> vt[d][s] f16.
__global__ __launch_bounds__(256) void rope_vred_kernel(
    const f16* __restrict__ qk, const double* __restrict__ freqs,
    f16* __restrict__ qr, f16* __restrict__ kr,
    const f16* __restrict__ vp, f16* __restrict__ vt) {
  __shared__ float tile[32][33];
  const int bid = blockIdx.x;
  if (bid < 4096) {
    const int s = bid;
    const int t = threadIdx.x;  // pairs 4t..4t+3 of this row
    f16x8 q8 = reinterpret_cast<const f16x8*>(qk + (size_t)s * 4096)[t];
    f16x8 k8 =
        reinterpret_cast<const f16x8*>(qk + (size_t)s * 4096 + 2048)[t];
    f16x8 qo, ko;
#pragma unroll
    for (int p = 0; p < 4; ++p) {
      double ang = (double)s * freqs[4 * t + p];
      ang -= 6.2831853071795864769 * floor(ang * 0.15915494309189533577);
      float c, sn;
      sincosf((float)ang, &sn, &c);
      const float qx = (float)q8[2 * p], qy = (float)q8[2 * p + 1];
      const float kx = (float)k8[2 * p], ky = (float)k8[2 * p + 1];
      qo[2 * p] = (f16)(qx * c - qy * sn);
      qo[2 * p + 1] = (f16)(qx * sn + qy * c);
      ko[2 * p] = (f16)(kx * c - ky * sn);
      ko[2 * p + 1] = (f16)(kx * sn + ky * c);
    }
    reinterpret_cast<f16x8*>(qr + (size_t)s * 2048)[t] = qo;
    reinterpret_cast<f16x8*>(kr + (size_t)s * 2048)[t] = ko;
  } else {
    const int vb = bid - 4096;             // 0..8191 = 128 x 64
    const int sblk = (vb & 127) * 32, dblk = (vb >> 7) * 32;
    const int tx = threadIdx.x & 31, ty = threadIdx.x >> 5;  // 32 x 8
#pragma unroll
    for (int i = 0; i < 4; ++i) {
      const size_t idx = (size_t)(sblk + ty + i * 8) * 2048 + dblk + tx;
      tile[ty + i * 8][tx] = (float)vp[idx] + (float)vp[idx + 8388608];
    }
    __syncthreads();
#pragma unroll
    for (int i = 0; i < 4; ++i)
      vt[(size_t)(dblk + ty + i * 8) * 4096 + sblk + tx] =
          (f16)tile[tx][ty + i * 8];
  }
}

// Row softmax: read f16 scores [row][4096], write fp32 weights (graded)
// and f16 copy for the PV GEMM.
__global__ __launch_bounds__(256) void softmax_kernel(
    const f16* __restrict__ sc, float* __restrict__ weights,
    f16* __restrict__ wh) {
  const int row = blockIdx.x;
  const f16x8* p = reinterpret_cast<const f16x8*>(sc + (size_t)row * 4096);
  const int tid = threadIdx.x;
  float v[16];
  float lmax = -3.0e38f;
#pragma unroll
  for (int i = 0; i < 2; ++i) {
    f16x8 h = p[tid + i * 256];
#pragma unroll
    for (int t = 0; t < 8; ++t) {
      v[i * 8 + t] = (float)h[t];
      lmax = fmaxf(lmax, v[i * 8 + t]);
    }
  }
#pragma unroll
  for (int o = 32; o >= 1; o >>= 1) lmax = fmaxf(lmax, __shfl_xor(lmax, o));
  __shared__ float redm[4], reds[4];
  if ((tid & 63) == 0) redm[tid >> 6] = lmax;
  __syncthreads();
  const float gmax = fmaxf(fmaxf(redm[0], redm[1]), fmaxf(redm[2], redm[3]));
  float lsum = 0.f;
#pragma unroll
  for (int t = 0; t < 16; ++t) {
    v[t] = expf(v[t] - gmax);
    lsum += v[t];
  }
#pragma unroll
  for (int o = 32; o >= 1; o >>= 1) lsum += __shfl_xor(lsum, o);
  if ((tid & 63) == 0) reds[tid >> 6] = lsum;
  __syncthreads();
  const float inv = 1.0f / (reds[0] + reds[1] + reds[2] + reds[3]);
  float* wrow = weights + (size_t)row * 4096;
  f16* hrow = wh + (size_t)row * 4096;
#pragma unroll
  for (int i = 0; i < 2; ++i) {
    const int base = (tid + i * 256) * 8;
    float w[8];
    f16x8 h;
#pragma unroll
    for (int t = 0; t < 8; ++t) {
      w[t] = v[i * 8 + t] * inv;
      h[t] = (f16)w[t];
    }
    *reinterpret_cast<float4*>(wrow + base) =
        make_float4(w[0], w[1], w[2], w[3]);
    *reinterpret_cast<float4*>(wrow + base + 4) =
        make_float4(w[4], w[5], w[6], w[7]);
    *reinterpret_cast<f16x8*>(hrow + base) = h;
  }
}

// out(fp32) = (float)p[0..8M) + (float)p[8M..16M), f16x8-vectorized
__global__ __launch_bounds__(256) void reduce2_kernel(
    const f16* __restrict__ p, float* __restrict__ out) {
  int i = blockIdx.x * 256 + threadIdx.x;  // f16x8 unit over 1M
  f16x8 a = reinterpret_cast<const f16x8*>(p)[i];
  f16x8 b = reinterpret_cast<const f16x8*>(p + 8388608)[i];
  float4 o0, o1;
#pragma unroll
  for (int t = 0; t < 4; ++t) ((float*)&o0)[t] = (float)a[t] + (float)b[t];
#pragma unroll
  for (int t = 0; t < 4; ++t) ((float*)&o1)[t] = (float)a[4 + t] + (float)b[4 + t];
  reinterpret_cast<float4*>(out)[2 * i] = o0;
  reinterpret_cast<float4*>(out)[2 * i + 1] = o1;
}

extern "C" void kernel_launch(void* const* d_in, const int* in_sizes, int n_in,
                              void* d_out, int out_size, void* d_ws,
                              size_t ws_size, hipStream_t stream) {
  const int S = 4096, D = 2048;
  const float* x = (const float*)d_in[0];
  const float* Wq = (const float*)d_in[1];
  const float* Wk = (const float*)d_in[2];
  const float* Wv = (const float*)d_in[3];
  float* out = (float*)d_out;            // [S, D]
  float* weights = out + (size_t)S * D;  // [S, S]

  f16* x_h = (f16*)d_ws;                           // S*D f16 (16MB)
  f16* w_h = x_h + (size_t)S * D;                  // 3*D*D f16 (24MB)
  f16* qk_h = w_h + (size_t)3 * D * D;             // S x 4096 f16 (32MB)
  f16* vp_h = qk_h + (size_t)S * 4096;             // 2 x S*D f16 (32MB)
  f16* qr = vp_h + (size_t)2 * S * D;              // S*D (16MB)
  f16* kr = qr + (size_t)S * D;                    // S*D (16MB)
  f16* vt = kr + (size_t)S * D;                    // D x S (16MB)
  f16* wsm = vt + (size_t)S * D;                   // S*S (32MB)
  double* freqs = (double*)(wsm + (size_t)S * S);  // 1024
  f16* sch = vp_h;   // f16 scores scratch (32MB; vp dead after vred)
  f16* pvp_h = qk_h; // PV f16 partials (32MB; qk dead after rope)

  cast_all_kernel<<<20480, 256, 0, stream>>>(x, Wq, Wk, Wv, x_h, w_h, freqs);

  // Combined QK (z=0: M=4096 N=4096 K=2048) + V (z=1: split-K=2, N=2048),
  // 512 blocks: 2 rounds with tail smoothing, one launch gap saved.
  gemm256_8ph<f16, 1><<<dim3(16, 16, 2), 512, 0, stream>>>(
      x_h, w_h, qk_h, S, 2 * D, D, D, 1.0f, w_h + (size_t)2 * D * D, vp_h);

  // RoPE (4096 blocks, one row each) + V reduce/transpose (8192 blocks)
  rope_vred_kernel<<<12288, 256, 0, stream>>>(qk_h, freqs, qr, kr, vp_h, vt);

  // scores = Q_rot @ K_rot^T / sqrt(D) -> f16 scratch: 256 blocks
  gemm256_8ph<f16, 0><<<dim3(16, 16, 1), 512, 0, stream>>>(
      qr, kr, sch, S, S, D, D, 0.02209708691207961f, nullptr, nullptr);
  softmax_kernel<<<S, 256, 0, stream>>>(sch, weights, wsm);

  // output = wsm[S,S] @ vt[D,S]^T, split-K=2 -> f16 partials: 256 blocks
  gemm256_8ph<f16, 0><<<dim3(8, 16, 2), 512, 0, stream>>>(
      wsm, vt, pvp_h, S, D, S / 2, S, 1.0f, nullptr, nullptr);
  reduce2_kernel<<<4096, 256, 0, stream>>>(pvp_h, out);
}